// Round 10
// baseline (562.850 us; speedup 1.0000x reference)
//
#include <hip/hip_runtime.h>
#include <hip/hip_bf16.h>
#include <math.h>

#define N_NODES 8192
#define IN_F    512
#define OUT_F   128
#define LRELU_A 0.2f
#define EPS_BN  1e-5f
#define MSH     40.0f                // static softmax shift (upper bound on lrelu(max s1+max s2))
#define NSPLIT  4
#define JSPAN   (N_NODES / NSPLIT)   // 2048
#define TILE_I  64                   // 8 waves = 4 i-blocks x 2 c-halves

typedef unsigned short u16;
typedef unsigned int   u32;
typedef unsigned long long u64;
typedef __attribute__((ext_vector_type(8))) short  short8;
typedef __attribute__((ext_vector_type(4))) float  floatx4;

__device__ __forceinline__ u16 f2bf_rtn(float x) {
    u32 u = __float_as_uint(x);
    return (u16)((u + 0x7fffu + ((u >> 16) & 1u)) >> 16);
}

// ---------------- adj -> bitmask (8 MB), pure HBM stream ----------------
// grid 2048 x 256 thr. wave = one row; 32 groups of 256 j; 1 KB coalesced read per load.
__global__ __launch_bounds__(256) void k_pack(const int* __restrict__ adj, u32* __restrict__ mask) {
    const int t = threadIdx.x;
    const int lane = t & 63, wid = t >> 6;
    const int row = blockIdx.x * 4 + wid;
    const int* ap = adj + (size_t)row * N_NODES + lane * 4;
    u32* mp = mask + (size_t)row * 256;
    uint4 cur = *(const uint4*)(ap);
#pragma unroll 4
    for (int g = 0; g < 32; ++g) {
        uint4 nxt = cur;
        if (g + 1 < 32) nxt = *(const uint4*)(ap + (g + 1) * 256);
        u64 b0 = __ballot((int)cur.x > 0);
        u64 b1 = __ballot((int)cur.y > 0);
        u64 b2 = __ballot((int)cur.z > 0);
        u64 b3 = __ballot((int)cur.w > 0);
        if (lane < 4) {
            u64 v = (lane == 0) ? b0 : (lane == 1) ? b1 : (lane == 2) ? b2 : b3;
            *(u64*)(mp + g * 8 + lane * 2) = v;
        }
        cur = nxt;
    }
}

// ---------------- hamT bf16 [128 c][512 k] from W; zero cs/cq ----------------
// hamilton[k=p*128+q][c=b*32+cc] = sgn(b,p) * W[q*128 + (b^p)*32 + cc]
__global__ __launch_bounds__(256) void k_hamT(const float* __restrict__ W, u16* __restrict__ hamT,
                                              float* __restrict__ cs, float* __restrict__ cq) {
    const int idx = blockIdx.x * 256 + threadIdx.x;   // 65536
    if (blockIdx.x == 0 && threadIdx.x < OUT_F) { cs[threadIdx.x] = 0.f; cq[threadIdx.x] = 0.f; }
    const int c = idx >> 9, k = idx & 511;
    const int b = c >> 5, cc = c & 31, p = k >> 7, q = k & 127;
    const u32 NEGMASK = 0x284Eu;     // bit (b*4+p) set => sign -1
    const float sg = ((NEGMASK >> (b * 4 + p)) & 1u) ? -1.f : 1.f;
    hamT[idx] = f2bf_rtn(sg * W[q * 128 + (b ^ p) * 32 + cc]);
}

// ---------------- h = input @ ham via MFMA; emit hT bf16 + s1/s2 ----------------
// grid 128 x 256 thr (4 waves). Block = 64 i; wave = 16 i x 128 c. K=512 in 16 steps.
__global__ __launch_bounds__(256) void k_h(const float* __restrict__ inp, const u16* __restrict__ hamT,
                                           const float* __restrict__ a,
                                           u16* __restrict__ hT, float* __restrict__ s1, float* __restrict__ s2) {
    const int t = threadIdx.x;
    const int lane = t & 63, wid = t >> 6;
    const int quad = lane >> 4, n = lane & 15;
    const int iw = blockIdx.x * 64 + wid * 16;     // wave's 16-row tile base
    floatx4 acc[8];
#pragma unroll
    for (int ct = 0; ct < 8; ct++) acc[ct] = (floatx4){0.f, 0.f, 0.f, 0.f};

    const float* arow = inp + (size_t)(iw + n) * IN_F + quad * 8;
#pragma unroll 4
    for (int kk = 0; kk < 16; ++kk) {
        float4 f0 = *(const float4*)(arow + kk * 32);
        float4 f1 = *(const float4*)(arow + kk * 32 + 4);
        union { u32 u[4]; short8 s; } fa;
        fa.u[0] = (u32)f2bf_rtn(f0.x) | ((u32)f2bf_rtn(f0.y) << 16);
        fa.u[1] = (u32)f2bf_rtn(f0.z) | ((u32)f2bf_rtn(f0.w) << 16);
        fa.u[2] = (u32)f2bf_rtn(f1.x) | ((u32)f2bf_rtn(f1.y) << 16);
        fa.u[3] = (u32)f2bf_rtn(f1.z) | ((u32)f2bf_rtn(f1.w) << 16);
#pragma unroll
        for (int ct = 0; ct < 8; ++ct) {
            short8 fb = *(const short8*)&hamT[(ct * 16 + n) * IN_F + kk * 32 + quad * 8];
            acc[ct] = __builtin_amdgcn_mfma_f32_16x16x32_bf16(fa.s, fb, acc[ct], 0, 0, 0);
        }
    }

    // ---- hT store: C layout row=quad*4+r, col=ct*16+n; pack 4 rows into u64 ----
#pragma unroll
    for (int ct = 0; ct < 8; ++ct) {
        u64 pk = (u64)f2bf_rtn(acc[ct][0])
               | ((u64)f2bf_rtn(acc[ct][1]) << 16)
               | ((u64)f2bf_rtn(acc[ct][2]) << 32)
               | ((u64)f2bf_rtn(acc[ct][3]) << 48);
        *(u64*)&hT[(size_t)(ct * 16 + n) * N_NODES + iw + quad * 4] = pk;
    }

    // ---- s1/s2 from f32 acc: per-lane partials over its 8 cols, reduce across n ----
    float p1[4] = {0.f, 0.f, 0.f, 0.f}, p2[4] = {0.f, 0.f, 0.f, 0.f};
#pragma unroll
    for (int ct = 0; ct < 8; ++ct) {
        const float a1v = a[ct * 16 + n], a2v = a[OUT_F + ct * 16 + n];
#pragma unroll
        for (int r = 0; r < 4; ++r) { p1[r] += acc[ct][r] * a1v; p2[r] += acc[ct][r] * a2v; }
    }
#pragma unroll
    for (int m = 1; m < 16; m <<= 1) {
#pragma unroll
        for (int r = 0; r < 4; ++r) {
            p1[r] += __shfl_xor(p1[r], m, 64);
            p2[r] += __shfl_xor(p2[r], m, 64);
        }
    }
    if (n == 0) {
#pragma unroll
        for (int r = 0; r < 4; ++r) {
            s1[iw + quad * 4 + r] = p1[r];
            s2[iw + quad * 4 + r] = p2[r];
        }
    }
}

// ---------------- MFMA attention: bitmask + direct-global B-frags, barrier-free j-loop ----------------
// grid (128, NSPLIT) x 512 thr. Block: 64 i x 128 c; wave: 16 i x 64 c (ib = wid>>1, ch = wid&1).
__global__ __launch_bounds__(512, 4) void k_att(const u32* __restrict__ mask, const u16* __restrict__ hT,
                                                const float* __restrict__ s1, const float* __restrict__ s2,
                                                float* __restrict__ Opart, float* __restrict__ Lpart) {
    __shared__ float s2s[JSPAN];   // 8 KB
    const int t = threadIdx.x;
    const int lane = t & 63, wid = t >> 6;
    const int quad = lane >> 4, n = lane & 15;
    const int ib = wid >> 1, ch = wid & 1;
    const int i0 = blockIdx.x * TILE_I;
    const int jbase = blockIdx.y * JSPAN;
    const int i_lane = i0 + ib * 16 + n;
    const float s1v = s1[i_lane];

    {   // stage s2 slice (8 KB) with 512 threads
        const int o = t * 4;
        *(float4*)&s2s[o] = *(const float4*)&s2[jbase + o];
    }

    const u32* mrow = mask + (size_t)i_lane * 256 + (jbase >> 5);
    uint4 mgA = *(const uint4*)(mrow);
    uint4 mgB = *(const uint4*)(mrow + 4);

    floatx4 acc[4];
#pragma unroll
    for (int ct = 0; ct < 4; ct++) acc[ct] = (floatx4){0.f, 0.f, 0.f, 0.f};
    float Lacc = 0.f;
    const int quad2 = quad * 2;

    __syncthreads();   // s2s ready; no barriers after this

#pragma unroll 2
    for (int g = 0; g < 8; ++g) {                 // 8 groups of 256 j
        uint4 mgA_n = mgA, mgB_n = mgB;
        if (g + 1 < 8) {
            mgA_n = *(const uint4*)(mrow + (g + 1) * 8);
            mgB_n = *(const uint4*)(mrow + (g + 1) * 8 + 4);
        }
        const u32 mg[8] = {mgA.x, mgA.y, mgA.z, mgA.w, mgB.x, mgB.y, mgB.z, mgB.w};
#pragma unroll
        for (int p = 0; p < 2; ++p) {             // 2 chunks of 128 j per group
            const int jc = g * 2 + p;
            // --- issue this chunk's B-frag loads (16 x b128, L2-hot hT) ---
            short8 fb[16];
#pragma unroll
            for (int ct = 0; ct < 4; ++ct) {
                const u16* hr = hT + (size_t)((ch * 4 + ct) * 16 + n) * N_NODES
                              + jbase + jc * 128 + quad * 8;
#pragma unroll
                for (int ks = 0; ks < 4; ++ks)
                    fb[ct * 4 + ks] = *(const short8*)(hr + ks * 32);
            }
            // --- build A-frags (w weights) while B loads fly ---
            short8 fa[4];
#pragma unroll
            for (int ks = 0; ks < 4; ++ks) {
                const int jl = jc * 128 + ks * 32 + quad * 8;
                float4 sa = *(const float4*)&s2s[jl];
                float4 sb = *(const float4*)&s2s[jl + 4];
                const float sv[8] = {sa.x, sa.y, sa.z, sa.w, sb.x, sb.y, sb.z, sb.w};
                union { u32 u[4]; short8 s; } cv;
#pragma unroll
                for (int jh = 0; jh < 4; ++jh) {
                    float w2[2];
#pragma unroll
                    for (int e = 0; e < 2; ++e) {
                        const int jj = jh * 2 + e;
                        const u32 word = mg[(jj & 3) * 2 + p];
                        const u32 mbit = (word >> (ks * 8 + quad2 + (jj >> 2))) & 1u;
                        float sc = s1v + sv[jj];
                        sc = fmaxf(sc, LRELU_A * sc);
                        float w = mbit ? __expf(sc - MSH) : 0.f;
                        Lacc += w;
                        w2[e] = w;
                    }
                    cv.u[jh] = (u32)f2bf_rtn(w2[0]) | ((u32)f2bf_rtn(w2[1]) << 16);
                }
                fa[ks] = cv.s;
            }
            // --- 16 MFMAs ---
#pragma unroll
            for (int ks = 0; ks < 4; ++ks)
#pragma unroll
                for (int ct = 0; ct < 4; ++ct)
                    acc[ct] = __builtin_amdgcn_mfma_f32_16x16x32_bf16(fa[ks], fb[ct * 4 + ks], acc[ct], 0, 0, 0);
        }
        mgA = mgA_n; mgB = mgB_n;
    }

    // L row-sum across quads (both c-halves compute it; only ch==0 stores)
    Lacc += __shfl_xor(Lacc, 16, 64);
    Lacc += __shfl_xor(Lacc, 32, 64);
    if (ch == 0 && lane < 16)
        Lpart[(size_t)blockIdx.y * N_NODES + i_lane] = Lacc;

    // O partials (C layout: row = quad*4+reg, col = n)
    const size_t obase = (size_t)blockIdx.y * N_NODES * OUT_F;
#pragma unroll
    for (int ct = 0; ct < 4; ++ct) {
#pragma unroll
        for (int r = 0; r < 4; ++r) {
            const int i = i0 + ib * 16 + quad * 4 + r;
            Opart[obase + (size_t)i * OUT_F + (ch * 4 + ct) * 16 + n] = acc[ct][r];
        }
    }
}

// ---------------- combine partials, normalize, column stats via atomics ----------------
// grid 512 x 256 thr; block = 16 i-rows
__global__ __launch_bounds__(256) void k_comb(const float* __restrict__ Opart, const float* __restrict__ Lpart,
                                              float* __restrict__ hp, float* __restrict__ cs, float* __restrict__ cq) {
    const int t = threadIdx.x;
    const int c = t & 127, half = t >> 7;
    const int ibase = blockIdx.x * 16;
    float sv = 0.f, sq = 0.f;
    for (int k = 0; k < 8; k++) {
        const int i = ibase + half + (k << 1);
        float o = 0.f, L = 0.f;
#pragma unroll
        for (int s = 0; s < NSPLIT; s++) {
            o += Opart[((size_t)s * N_NODES + i) * OUT_F + c];
            L += Lpart[(size_t)s * N_NODES + i];
        }
        float v = L > 0.f ? o / L : 0.f;
        hp[(size_t)i * OUT_F + c] = v;
        sv += v; sq += v * v;
    }
    __shared__ float red[256];
    red[t] = sv; __syncthreads();
    if (half == 0) atomicAdd(&cs[c], sv + red[t + 128]);
    __syncthreads(); red[t] = sq; __syncthreads();
    if (half == 0) atomicAdd(&cq[c], sq + red[t + 128]);
}

// ---------------- batchnorm + elu + f32 out ----------------
__global__ __launch_bounds__(256) void k_bn(const float* __restrict__ hp, const float* __restrict__ cs,
                                            const float* __restrict__ cq, const float* __restrict__ gamma,
                                            const float* __restrict__ beta, float* __restrict__ out) {
    const int idx = blockIdx.x * 256 + threadIdx.x;   // 1M
    const int c = idx & 127;
    const float mean = cs[c] * (1.f / N_NODES);
    const float var  = cq[c] * (1.f / N_NODES) - mean * mean;
    float x = (hp[idx] - mean) * rsqrtf(var + EPS_BN) * gamma[c] + beta[c];
    x = x > 0.f ? x : expm1f(x);
    out[idx] = x;
}

extern "C" void kernel_launch(void* const* d_in, const int* in_sizes, int n_in,
                              void* d_out, int out_size, void* d_ws, size_t ws_size,
                              hipStream_t stream) {
    (void)in_sizes; (void)n_in; (void)out_size; (void)ws_size;
    const float* inp   = (const float*)d_in[0];
    const int*   adj   = (const int*)d_in[1];
    const float* W     = (const float*)d_in[2];
    const float* a     = (const float*)d_in[3];
    const float* gamma = (const float*)d_in[4];
    const float* beta  = (const float*)d_in[5];
    float* out = (float*)d_out;

    char* wsb = (char*)d_ws;
    u16*   hamT = (u16*)wsb;   wsb += (size_t)OUT_F * IN_F * 2;               // 128 KB
    u16*   hT   = (u16*)wsb;   wsb += (size_t)OUT_F * N_NODES * 2;            // 2 MB
    float* s1   = (float*)wsb; wsb += N_NODES * 4;
    float* s2   = (float*)wsb; wsb += N_NODES * 4;
    u32*   mask = (u32*)wsb;   wsb += (size_t)N_NODES * 256 * 4;              // 8 MB
    float* Op   = (float*)wsb; wsb += (size_t)NSPLIT * N_NODES * OUT_F * 4;   // 16 MB
    float* Lp   = (float*)wsb; wsb += (size_t)NSPLIT * N_NODES * 4;
    float* hp   = (float*)wsb; wsb += (size_t)N_NODES * OUT_F * 4;            // 4 MB
    float* cs   = (float*)wsb; wsb += OUT_F * 4;
    float* cq   = (float*)wsb; wsb += OUT_F * 4;

    hipLaunchKernelGGL(k_pack, dim3(2048), dim3(256), 0, stream, adj, mask);
    hipLaunchKernelGGL(k_hamT, dim3(256), dim3(256), 0, stream, W, hamT, cs, cq);
    hipLaunchKernelGGL(k_h,    dim3(128), dim3(256), 0, stream, inp, hamT, a, hT, s1, s2);
    hipLaunchKernelGGL(k_att,  dim3(128, NSPLIT), dim3(512), 0, stream, mask, hT, s1, s2, Op, Lp);
    hipLaunchKernelGGL(k_comb, dim3(512), dim3(256), 0, stream, Op, Lp, hp, cs, cq);
    hipLaunchKernelGGL(k_bn,   dim3(4096), dim3(256), 0, stream, hp, cs, cq, gamma, beta, out);
}

// Round 11
// 495.301 us; speedup vs baseline: 1.1364x; 1.1364x over previous
//
#include <hip/hip_runtime.h>
#include <hip/hip_bf16.h>
#include <math.h>

#define N_NODES 8192
#define IN_F    512
#define OUT_F   128
#define LRELU_A 0.2f
#define EPS_BN  1e-5f
#define MSH     40.0f                // static softmax shift (upper bound on lrelu(max s1+max s2))
#define NSPLIT  8
#define JSPAN   (N_NODES / NSPLIT)   // 1024
#define TILE_I  64                   // 4 waves x 16 rows
#define HSTR    72                   // LDS row stride (64 + 8 pad) in shorts
#define ASTR    36                   // k_h A-tile row stride (32 + 4 pad) in floats

typedef unsigned short u16;
typedef unsigned int   u32;
typedef unsigned long long u64;
typedef __attribute__((ext_vector_type(8))) short  short8;
typedef __attribute__((ext_vector_type(4))) float  floatx4;

__device__ __forceinline__ u16 f2bf_rtn(float x) {
    u32 u = __float_as_uint(x);
    return (u16)((u + 0x7fffu + ((u >> 16) & 1u)) >> 16);
}

// ---------------- adj -> bitmask (8 MB), pure HBM stream (coalesced 1 KB/instr) ----------------
// j = g*256 + 4*l + comp  ->  word row*256 + g*8 + comp*2 + (l>>5), bit l&31
__global__ __launch_bounds__(256) void k_pack(const int* __restrict__ adj, u32* __restrict__ mask) {
    const int t = threadIdx.x;
    const int lane = t & 63, wid = t >> 6;
    const int row = blockIdx.x * 4 + wid;
    const int* ap = adj + (size_t)row * N_NODES + lane * 4;
    u32* mp = mask + (size_t)row * 256;
    uint4 cur = *(const uint4*)(ap);
#pragma unroll 4
    for (int g = 0; g < 32; ++g) {
        uint4 nxt = cur;
        if (g + 1 < 32) nxt = *(const uint4*)(ap + (g + 1) * 256);
        u64 b0 = __ballot((int)cur.x > 0);
        u64 b1 = __ballot((int)cur.y > 0);
        u64 b2 = __ballot((int)cur.z > 0);
        u64 b3 = __ballot((int)cur.w > 0);
        if (lane < 4) {
            u64 v = (lane == 0) ? b0 : (lane == 1) ? b1 : (lane == 2) ? b2 : b3;
            *(u64*)(mp + g * 8 + lane * 2) = v;
        }
        cur = nxt;
    }
}

// ---------------- hamT bf16 [128 c][512 k]; zero s1/s2/cs/cq ----------------
__global__ __launch_bounds__(256) void k_hamT(const float* __restrict__ W, u16* __restrict__ hamT,
                                              float* __restrict__ s1, float* __restrict__ s2,
                                              float* __restrict__ cs, float* __restrict__ cq) {
    const int idx = blockIdx.x * 256 + threadIdx.x;   // 65536
    if (idx < N_NODES) { s1[idx] = 0.f; s2[idx] = 0.f; }
    if (idx < OUT_F)   { cs[idx] = 0.f; cq[idx] = 0.f; }
    const int c = idx >> 9, k = idx & 511;
    const int b = c >> 5, cc = c & 31, p = k >> 7, q = k & 127;
    const u32 NEGMASK = 0x284Eu;     // bit (b*4+p) set => sign -1
    const float sg = ((NEGMASK >> (b * 4 + p)) & 1u) ? -1.f : 1.f;
    hamT[idx] = f2bf_rtn(sg * W[q * 128 + (b ^ p) * 32 + cc]);
}

// ---------------- h = input @ ham via MFMA; LDS-staged A (coalesced); emit hT + s1/s2 ----------------
// grid (128, 2) x 256 thr. Block: 64 i x 64 c (c-half); wave = 16 i x 64 c. K=512 in 16 steps.
__global__ __launch_bounds__(256) void k_h(const float* __restrict__ inp, const u16* __restrict__ hamT,
                                           const float* __restrict__ a,
                                           u16* __restrict__ hT, float* __restrict__ s1, float* __restrict__ s2) {
    __shared__ float inA[2][64 * ASTR];    // 2 x 9216 B
    const int t = threadIdx.x;
    const int lane = t & 63, wid = t >> 6;
    const int quad = lane >> 4, n = lane & 15;
    const int i0 = blockIdx.x * 64;
    const int chalf = blockIdx.y;
    const int srow = t >> 2, scol = (t & 3) * 8;     // staging map: 64 B per thread per step

    // stage step 0
    {
        const float* sp = inp + (size_t)(i0 + srow) * IN_F + scol;
        *(float4*)&inA[0][srow * ASTR + scol]     = *(const float4*)sp;
        *(float4*)&inA[0][srow * ASTR + scol + 4] = *(const float4*)(sp + 4);
    }
    __syncthreads();

    floatx4 acc[4];
#pragma unroll
    for (int ct = 0; ct < 4; ct++) acc[ct] = (floatx4){0.f, 0.f, 0.f, 0.f};

#pragma unroll 2
    for (int kk = 0; kk < 16; ++kk) {
        const int cur = kk & 1;
        float4 f0n, f1n;
        const bool more = (kk + 1 < 16);
        if (more) {
            const float* sp = inp + (size_t)(i0 + srow) * IN_F + (kk + 1) * 32 + scol;
            f0n = *(const float4*)sp;
            f1n = *(const float4*)(sp + 4);
        }
        // A-frag from LDS: row wid*16+n, k quad*8..+8
        float4 a0 = *(const float4*)&inA[cur][(wid * 16 + n) * ASTR + quad * 8];
        float4 a1 = *(const float4*)&inA[cur][(wid * 16 + n) * ASTR + quad * 8 + 4];
        union { u32 u[4]; short8 s; } fa;
        fa.u[0] = (u32)f2bf_rtn(a0.x) | ((u32)f2bf_rtn(a0.y) << 16);
        fa.u[1] = (u32)f2bf_rtn(a0.z) | ((u32)f2bf_rtn(a0.w) << 16);
        fa.u[2] = (u32)f2bf_rtn(a1.x) | ((u32)f2bf_rtn(a1.y) << 16);
        fa.u[3] = (u32)f2bf_rtn(a1.z) | ((u32)f2bf_rtn(a1.w) << 16);
#pragma unroll
        for (int ct = 0; ct < 4; ++ct) {
            short8 fb = *(const short8*)&hamT[(chalf * 64 + ct * 16 + n) * IN_F + kk * 32 + quad * 8];
            acc[ct] = __builtin_amdgcn_mfma_f32_16x16x32_bf16(fa.s, fb, acc[ct], 0, 0, 0);
        }
        if (more) {
            *(float4*)&inA[cur ^ 1][srow * ASTR + scol]     = f0n;
            *(float4*)&inA[cur ^ 1][srow * ASTR + scol + 4] = f1n;
        }
        __syncthreads();
    }

    // hT store (C layout: row=quad*4+r, col=chalf*64+ct*16+n); pack 4 rows -> u64
    const int iw = i0 + wid * 16;
#pragma unroll
    for (int ct = 0; ct < 4; ++ct) {
        const int c = chalf * 64 + ct * 16 + n;
        u64 pk = (u64)f2bf_rtn(acc[ct][0])
               | ((u64)f2bf_rtn(acc[ct][1]) << 16)
               | ((u64)f2bf_rtn(acc[ct][2]) << 32)
               | ((u64)f2bf_rtn(acc[ct][3]) << 48);
        *(u64*)&hT[(size_t)c * N_NODES + iw + quad * 4] = pk;
    }

    // s1/s2 partials (this c-half) -> global atomics
    float p1[4] = {0.f, 0.f, 0.f, 0.f}, p2[4] = {0.f, 0.f, 0.f, 0.f};
#pragma unroll
    for (int ct = 0; ct < 4; ++ct) {
        const int c = chalf * 64 + ct * 16 + n;
        const float a1v = a[c], a2v = a[OUT_F + c];
#pragma unroll
        for (int r = 0; r < 4; ++r) { p1[r] += acc[ct][r] * a1v; p2[r] += acc[ct][r] * a2v; }
    }
#pragma unroll
    for (int m = 1; m < 16; m <<= 1) {
#pragma unroll
        for (int r = 0; r < 4; ++r) {
            p1[r] += __shfl_xor(p1[r], m, 64);
            p2[r] += __shfl_xor(p2[r], m, 64);
        }
    }
    if (n == 0) {
#pragma unroll
        for (int r = 0; r < 4; ++r) {
            atomicAdd(&s1[iw + quad * 4 + r], p1[r]);
            atomicAdd(&s2[iw + quad * 4 + r], p2[r]);
        }
    }
}

// ---------------- MFMA attention: bitmask + coalesced LDS-staged hT, dbuf, 1 barrier/chunk ----------------
// grid (128, NSPLIT) x 256 thr. Block: 64 i x 128 c; wave = 16 i x 128 c; 16 chunks of 64 j.
__global__ __launch_bounds__(256, 3) void k_att(const u32* __restrict__ mask, const u16* __restrict__ hT,
                                                const float* __restrict__ s1, const float* __restrict__ s2,
                                                float* __restrict__ Opart, float* __restrict__ Lpart) {
    __shared__ u16 hs[2][128 * HSTR];      // 2 x 18432 B
    __shared__ float s2s[JSPAN];           // 4 KB
    const int t = threadIdx.x;
    const int lane = t & 63, wid = t >> 6;
    const int quad = lane >> 4, n = lane & 15;
    const int i0 = blockIdx.x * TILE_I;
    const int jbase = blockIdx.y * JSPAN;
    const int i_lane = i0 + wid * 16 + n;
    const float s1v = s1[i_lane];
    const int scr = t >> 3, scj = (t & 7) * 8;      // staging: 32 c-rows/pass, 16 B per thread

    if (t < 256) *(float4*)&s2s[t * 4] = *(const float4*)&s2[jbase + t * 4];

    const u32* mrow = mask + (size_t)i_lane * 256 + (jbase >> 5);
    uint4 mgA = *(const uint4*)(mrow);
    uint4 mgB = *(const uint4*)(mrow + 4);

    // stage chunk 0
#pragma unroll
    for (int ps = 0; ps < 4; ++ps) {
        const int cr = ps * 32 + scr;
        uint4 v = *(const uint4*)&hT[(size_t)cr * N_NODES + jbase + scj];
        *(uint4*)&hs[0][cr * HSTR + scj] = v;
    }
    __syncthreads();

    floatx4 acc[8];
#pragma unroll
    for (int ct = 0; ct < 8; ct++) acc[ct] = (floatx4){0.f, 0.f, 0.f, 0.f};
    float Lacc = 0.f;

#pragma unroll 4
    for (int ch = 0; ch < 16; ++ch) {
        const int cur = ch & 1;
        const bool more = (ch + 1 < 16);
        // prefetch next chunk's hT (regs; LDS write after compute)
        uint4 H[4];
        if (more) {
#pragma unroll
            for (int ps = 0; ps < 4; ++ps) {
                const int cr = ps * 32 + scr;
                H[ps] = *(const uint4*)&hT[(size_t)cr * N_NODES + jbase + (ch + 1) * 64 + scj];
            }
        }
        // prefetch next mask group at end of each 4-chunk group
        uint4 mgA_n = mgA, mgB_n = mgB;
        if ((ch & 3) == 3 && more) {
            mgA_n = *(const uint4*)(mrow + ((ch >> 2) + 1) * 8);
            mgB_n = *(const uint4*)(mrow + ((ch >> 2) + 1) * 8 + 4);
        }
        const u32 mg[8] = {mgA.x, mgA.y, mgA.z, mgA.w, mgB.x, mgB.y, mgB.z, mgB.w};

        // build A-frags (w) for this chunk's 64 j
        short8 fa[2];
#pragma unroll
        for (int ks = 0; ks < 2; ++ks) {
            const int jl = ch * 64 + ks * 32 + quad * 8;
            float4 sa = *(const float4*)&s2s[jl];
            float4 sb = *(const float4*)&s2s[jl + 4];
            const float sv[8] = {sa.x, sa.y, sa.z, sa.w, sb.x, sb.y, sb.z, sb.w};
            union { u32 u[4]; short8 s; } cv;
#pragma unroll
            for (int jh = 0; jh < 4; ++jh) {
                float w2[2];
#pragma unroll
                for (int e = 0; e < 2; ++e) {
                    const int jj = jh * 2 + e;
                    const u32 word = mg[(jj & 3) * 2 + ((ch >> 1) & 1)];
                    const int sh = (ch & 1) * 16 + ks * 8 + quad * 2 + (jj >> 2);
                    const u32 mbit = (word >> sh) & 1u;
                    float sc = s1v + sv[jj];
                    sc = fmaxf(sc, LRELU_A * sc);
                    float w = mbit ? __expf(sc - MSH) : 0.f;
                    Lacc += w;
                    w2[e] = w;
                }
                cv.u[jh] = (u32)f2bf_rtn(w2[0]) | ((u32)f2bf_rtn(w2[1]) << 16);
            }
            fa[ks] = cv.s;
        }
        // 16 MFMAs from LDS (padded stride: uniform banks)
#pragma unroll
        for (int ct = 0; ct < 8; ++ct) {
            const int boff = (ct * 16 + n) * HSTR;
            short8 fb0 = *(const short8*)&hs[cur][boff + quad * 8];
            short8 fb1 = *(const short8*)&hs[cur][boff + 32 + quad * 8];
            acc[ct] = __builtin_amdgcn_mfma_f32_16x16x32_bf16(fa[0], fb0, acc[ct], 0, 0, 0);
            acc[ct] = __builtin_amdgcn_mfma_f32_16x16x32_bf16(fa[1], fb1, acc[ct], 0, 0, 0);
        }
        // write prefetched chunk to alternate buffer
        if (more) {
#pragma unroll
            for (int ps = 0; ps < 4; ++ps) {
                const int cr = ps * 32 + scr;
                *(uint4*)&hs[cur ^ 1][cr * HSTR + scj] = H[ps];
            }
        }
        __syncthreads();
        mgA = mgA_n; mgB = mgB_n;
    }

    // L row-sum across quads
    Lacc += __shfl_xor(Lacc, 16, 64);
    Lacc += __shfl_xor(Lacc, 32, 64);
    if (lane < 16)
        Lpart[(size_t)blockIdx.y * N_NODES + i_lane] = Lacc;

    // O partials (C layout: row = quad*4+reg, col = ct*16+n)
    const size_t obase = (size_t)blockIdx.y * N_NODES * OUT_F;
#pragma unroll
    for (int ct = 0; ct < 8; ++ct) {
#pragma unroll
        for (int r = 0; r < 4; ++r) {
            const int i = i0 + wid * 16 + quad * 4 + r;
            Opart[obase + (size_t)i * OUT_F + ct * 16 + n] = acc[ct][r];
        }
    }
}

// ---------------- combine partials, normalize, column stats via atomics ----------------
// grid 512 x 256 thr; block = 16 i-rows
__global__ __launch_bounds__(256) void k_comb(const float* __restrict__ Opart, const float* __restrict__ Lpart,
                                              float* __restrict__ hp, float* __restrict__ cs, float* __restrict__ cq) {
    const int t = threadIdx.x;
    const int c = t & 127, half = t >> 7;
    const int ibase = blockIdx.x * 16;
    float sv = 0.f, sq = 0.f;
    for (int k = 0; k < 8; k++) {
        const int i = ibase + half + (k << 1);
        float o = 0.f, L = 0.f;
#pragma unroll
        for (int s = 0; s < NSPLIT; s++) {
            o += Opart[((size_t)s * N_NODES + i) * OUT_F + c];
            L += Lpart[(size_t)s * N_NODES + i];
        }
        float v = L > 0.f ? o / L : 0.f;
        hp[(size_t)i * OUT_F + c] = v;
        sv += v; sq += v * v;
    }
    __shared__ float red[256];
    red[t] = sv; __syncthreads();
    if (half == 0) atomicAdd(&cs[c], sv + red[t + 128]);
    __syncthreads(); red[t] = sq; __syncthreads();
    if (half == 0) atomicAdd(&cq[c], sq + red[t + 128]);
}

// ---------------- batchnorm + elu + f32 out ----------------
__global__ __launch_bounds__(256) void k_bn(const float* __restrict__ hp, const float* __restrict__ cs,
                                            const float* __restrict__ cq, const float* __restrict__ gamma,
                                            const float* __restrict__ beta, float* __restrict__ out) {
    const int idx = blockIdx.x * 256 + threadIdx.x;   // 1M
    const int c = idx & 127;
    const float mean = cs[c] * (1.f / N_NODES);
    const float var  = cq[c] * (1.f / N_NODES) - mean * mean;
    float x = (hp[idx] - mean) * rsqrtf(var + EPS_BN) * gamma[c] + beta[c];
    x = x > 0.f ? x : expm1f(x);
    out[idx] = x;
}

extern "C" void kernel_launch(void* const* d_in, const int* in_sizes, int n_in,
                              void* d_out, int out_size, void* d_ws, size_t ws_size,
                              hipStream_t stream) {
    (void)in_sizes; (void)n_in; (void)out_size; (void)ws_size;
    const float* inp   = (const float*)d_in[0];
    const int*   adj   = (const int*)d_in[1];
    const float* W     = (const float*)d_in[2];
    const float* a     = (const float*)d_in[3];
    const float* gamma = (const float*)d_in[4];
    const float* beta  = (const float*)d_in[5];
    float* out = (float*)d_out;

    char* wsb = (char*)d_ws;
    u16*   hamT = (u16*)wsb;   wsb += (size_t)OUT_F * IN_F * 2;               // 128 KB
    u16*   hT   = (u16*)wsb;   wsb += (size_t)OUT_F * N_NODES * 2;            // 2 MB
    float* s1   = (float*)wsb; wsb += N_NODES * 4;
    float* s2   = (float*)wsb; wsb += N_NODES * 4;
    u32*   mask = (u32*)wsb;   wsb += (size_t)N_NODES * 256 * 4;              // 8 MB
    float* Op   = (float*)wsb; wsb += (size_t)NSPLIT * N_NODES * OUT_F * 4;   // 32 MB
    float* Lp   = (float*)wsb; wsb += (size_t)NSPLIT * N_NODES * 4;
    float* hp   = (float*)wsb; wsb += (size_t)N_NODES * OUT_F * 4;            // 4 MB
    float* cs   = (float*)wsb; wsb += OUT_F * 4;
    float* cq   = (float*)wsb; wsb += OUT_F * 4;

    hipLaunchKernelGGL(k_pack, dim3(2048), dim3(256), 0, stream, adj, mask);
    hipLaunchKernelGGL(k_hamT, dim3(256), dim3(256), 0, stream, W, hamT, s1, s2, cs, cq);
    hipLaunchKernelGGL(k_h,    dim3(128, 2), dim3(256), 0, stream, inp, hamT, a, hT, s1, s2);
    hipLaunchKernelGGL(k_att,  dim3(128, NSPLIT), dim3(256), 0, stream, mask, hT, s1, s2, Op, Lp);
    hipLaunchKernelGGL(k_comb, dim3(512), dim3(256), 0, stream, Op, Lp, hp, cs, cq);
    hipLaunchKernelGGL(k_bn,   dim3(4096), dim3(256), 0, stream, hp, cs, cq, gamma, beta, out);
}

// Round 12
// 483.124 us; speedup vs baseline: 1.1650x; 1.0252x over previous
//
#include <hip/hip_runtime.h>
#include <hip/hip_bf16.h>
#include <math.h>

#define N_NODES 8192
#define IN_F    512
#define OUT_F   128
#define LRELU_A 0.2f
#define EPS_BN  1e-5f
#define MSH     40.0f                // static softmax shift (upper bound on lrelu(max s1+max s2))
#define NSPLIT  8
#define JSPAN   (N_NODES / NSPLIT)   // 1024
#define TILE_I  64                   // 4 waves x 16 rows
#define HSTR    72                   // LDS hT row stride (64 + 8 pad) in shorts
#define ASTR    36                   // k_h A-tile row stride (32 + 4 pad) in floats
#define MSTR    34                   // LDS mask row stride in u32 (32 + 2 pad, even for u64 align)

typedef unsigned short u16;
typedef unsigned int   u32;
typedef unsigned long long u64;
typedef __attribute__((ext_vector_type(8))) short  short8;
typedef __attribute__((ext_vector_type(4))) float  floatx4;

__device__ __forceinline__ u16 f2bf_rtn(float x) {
    u32 u = __float_as_uint(x);
    return (u16)((u + 0x7fffu + ((u >> 16) & 1u)) >> 16);
}

// ---------------- hamT bf16 [128 c][512 k]; zero s1/s2/cs/cq ----------------
__global__ __launch_bounds__(256) void k_hamT(const float* __restrict__ W, u16* __restrict__ hamT,
                                              float* __restrict__ s1, float* __restrict__ s2,
                                              float* __restrict__ cs, float* __restrict__ cq) {
    const int idx = blockIdx.x * 256 + threadIdx.x;   // 65536
    if (idx < N_NODES) { s1[idx] = 0.f; s2[idx] = 0.f; }
    if (idx < OUT_F)   { cs[idx] = 0.f; cq[idx] = 0.f; }
    const int c = idx >> 9, k = idx & 511;
    const int b = c >> 5, cc = c & 31, p = k >> 7, q = k & 127;
    const u32 NEGMASK = 0x284Eu;     // bit (b*4+p) set => sign -1
    const float sg = ((NEGMASK >> (b * 4 + p)) & 1u) ? -1.f : 1.f;
    hamT[idx] = f2bf_rtn(sg * W[q * 128 + (b ^ p) * 32 + cc]);
}

// ---------------- h = input @ ham via MFMA; LDS-staged A (coalesced); emit hT + s1/s2 ----------------
// grid (128, 2) x 256 thr. Block: 64 i x 64 c (c-half); wave = 16 i x 64 c. K=512 in 16 steps.
__global__ __launch_bounds__(256) void k_h(const float* __restrict__ inp, const u16* __restrict__ hamT,
                                           const float* __restrict__ a,
                                           u16* __restrict__ hT, float* __restrict__ s1, float* __restrict__ s2) {
    __shared__ float inA[2][64 * ASTR];    // 2 x 9216 B
    const int t = threadIdx.x;
    const int lane = t & 63, wid = t >> 6;
    const int quad = lane >> 4, n = lane & 15;
    const int i0 = blockIdx.x * 64;
    const int chalf = blockIdx.y;
    const int srow = t >> 2, scol = (t & 3) * 8;     // staging map: 64 B per thread per step

    // stage step 0
    {
        const float* sp = inp + (size_t)(i0 + srow) * IN_F + scol;
        *(float4*)&inA[0][srow * ASTR + scol]     = *(const float4*)sp;
        *(float4*)&inA[0][srow * ASTR + scol + 4] = *(const float4*)(sp + 4);
    }
    __syncthreads();

    floatx4 acc[4];
#pragma unroll
    for (int ct = 0; ct < 4; ct++) acc[ct] = (floatx4){0.f, 0.f, 0.f, 0.f};

#pragma unroll 2
    for (int kk = 0; kk < 16; ++kk) {
        const int cur = kk & 1;
        float4 f0n, f1n;
        const bool more = (kk + 1 < 16);
        if (more) {
            const float* sp = inp + (size_t)(i0 + srow) * IN_F + (kk + 1) * 32 + scol;
            f0n = *(const float4*)sp;
            f1n = *(const float4*)(sp + 4);
        }
        float4 a0 = *(const float4*)&inA[cur][(wid * 16 + n) * ASTR + quad * 8];
        float4 a1 = *(const float4*)&inA[cur][(wid * 16 + n) * ASTR + quad * 8 + 4];
        union { u32 u[4]; short8 s; } fa;
        fa.u[0] = (u32)f2bf_rtn(a0.x) | ((u32)f2bf_rtn(a0.y) << 16);
        fa.u[1] = (u32)f2bf_rtn(a0.z) | ((u32)f2bf_rtn(a0.w) << 16);
        fa.u[2] = (u32)f2bf_rtn(a1.x) | ((u32)f2bf_rtn(a1.y) << 16);
        fa.u[3] = (u32)f2bf_rtn(a1.z) | ((u32)f2bf_rtn(a1.w) << 16);
#pragma unroll
        for (int ct = 0; ct < 4; ++ct) {
            short8 fb = *(const short8*)&hamT[(chalf * 64 + ct * 16 + n) * IN_F + kk * 32 + quad * 8];
            acc[ct] = __builtin_amdgcn_mfma_f32_16x16x32_bf16(fa.s, fb, acc[ct], 0, 0, 0);
        }
        if (more) {
            *(float4*)&inA[cur ^ 1][srow * ASTR + scol]     = f0n;
            *(float4*)&inA[cur ^ 1][srow * ASTR + scol + 4] = f1n;
        }
        __syncthreads();
    }

    // hT store (C layout: row=quad*4+r, col=chalf*64+ct*16+n); pack 4 rows -> u64
    const int iw = i0 + wid * 16;
#pragma unroll
    for (int ct = 0; ct < 4; ++ct) {
        const int c = chalf * 64 + ct * 16 + n;
        u64 pk = (u64)f2bf_rtn(acc[ct][0])
               | ((u64)f2bf_rtn(acc[ct][1]) << 16)
               | ((u64)f2bf_rtn(acc[ct][2]) << 32)
               | ((u64)f2bf_rtn(acc[ct][3]) << 48);
        *(u64*)&hT[(size_t)c * N_NODES + iw + quad * 4] = pk;
    }

    // s1/s2 partials (this c-half) -> global atomics
    float p1[4] = {0.f, 0.f, 0.f, 0.f}, p2[4] = {0.f, 0.f, 0.f, 0.f};
#pragma unroll
    for (int ct = 0; ct < 4; ++ct) {
        const int c = chalf * 64 + ct * 16 + n;
        const float a1v = a[c], a2v = a[OUT_F + c];
#pragma unroll
        for (int r = 0; r < 4; ++r) { p1[r] += acc[ct][r] * a1v; p2[r] += acc[ct][r] * a2v; }
    }
#pragma unroll
    for (int m = 1; m < 16; m <<= 1) {
#pragma unroll
        for (int r = 0; r < 4; ++r) {
            p1[r] += __shfl_xor(p1[r], m, 64);
            p2[r] += __shfl_xor(p2[r], m, 64);
        }
    }
    if (n == 0) {
#pragma unroll
        for (int r = 0; r < 4; ++r) {
            atomicAdd(&s1[iw + quad * 4 + r], p1[r]);
            atomicAdd(&s2[iw + quad * 4 + r], p2[r]);
        }
    }
}

// ---------------- fused MFMA attention: inline adj->bitmask (coalesced) + LDS hT dbuf ----------------
// grid (128, NSPLIT) x 256 thr. Block: 64 i x 128 c over JSPAN=1024 j; 16 chunks of 64 j.
// Phase A: each wave ballot-packs its 16 adj rows into LDS masks (1 KB/instr coalesced).
// Phase B: R11's validated j-loop, masks from LDS.
__global__ __launch_bounds__(256, 3) void k_att(const int* __restrict__ adj, const u16* __restrict__ hT,
                                                const float* __restrict__ s1, const float* __restrict__ s2,
                                                float* __restrict__ Opart, float* __restrict__ Lpart) {
    __shared__ u16 hs[2][128 * HSTR];      // 2 x 18432 B
    __shared__ float s2s[JSPAN];           // 4 KB
    __shared__ u32 mk[64 * MSTR];          // 8704 B
    const int t = threadIdx.x;
    const int lane = t & 63, wid = t >> 6;
    const int quad = lane >> 4, n = lane & 15;
    const int i0 = blockIdx.x * TILE_I;
    const int jbase = blockIdx.y * JSPAN;
    const int i_lane = i0 + wid * 16 + n;
    const float s1v = s1[i_lane];
    const int scr = t >> 3, scj = (t & 7) * 8;      // hT staging: 32 c-rows/pass, 16 B/thread

    *(float4*)&s2s[t * 4] = *(const float4*)&s2[jbase + t * 4];

    // ---- Phase A: pack this wave's 16 rows of adj into LDS masks ----
    {
        const size_t rowbase = (size_t)(i0 + wid * 16);
#pragma unroll
        for (int rb = 0; rb < 4; ++rb) {
            uint4 v[4][4];
#pragma unroll
            for (int r = 0; r < 4; ++r) {
                const int* ap = adj + (rowbase + rb * 4 + r) * N_NODES + jbase + lane * 4;
#pragma unroll
                for (int g = 0; g < 4; ++g) v[r][g] = *(const uint4*)(ap + g * 256);
            }
#pragma unroll
            for (int r = 0; r < 4; ++r) {
                u32* mp = &mk[(wid * 16 + rb * 4 + r) * MSTR];
#pragma unroll
                for (int g = 0; g < 4; ++g) {
                    u64 c0 = __ballot((int)v[r][g].x > 0);
                    u64 c1 = __ballot((int)v[r][g].y > 0);
                    u64 c2 = __ballot((int)v[r][g].z > 0);
                    u64 c3 = __ballot((int)v[r][g].w > 0);
                    if (lane < 4) {
                        u64 val = (lane == 0) ? c0 : (lane == 1) ? c1 : (lane == 2) ? c2 : c3;
                        *(u64*)&mp[g * 8 + lane * 2] = val;
                    }
                }
            }
        }
    }

    // ---- stage hT chunk 0 ----
#pragma unroll
    for (int ps = 0; ps < 4; ++ps) {
        const int cr = ps * 32 + scr;
        uint4 v = *(const uint4*)&hT[(size_t)cr * N_NODES + jbase + scj];
        *(uint4*)&hs[0][cr * HSTR + scj] = v;
    }
    __syncthreads();

    // my row's group-0 mask words
    u32 m8[8];
    {
        const u32* mp = &mk[(wid * 16 + n) * MSTR];
#pragma unroll
        for (int w = 0; w < 8; ++w) m8[w] = mp[w];
    }

    floatx4 acc[8];
#pragma unroll
    for (int ct = 0; ct < 8; ct++) acc[ct] = (floatx4){0.f, 0.f, 0.f, 0.f};
    float Lacc = 0.f;

#pragma unroll 4
    for (int ch = 0; ch < 16; ++ch) {
        const int cur = ch & 1;
        const bool more = (ch + 1 < 16);
        // prefetch next chunk's hT (regs; LDS write after compute)
        uint4 H[4];
        if (more) {
#pragma unroll
            for (int ps = 0; ps < 4; ++ps) {
                const int cr = ps * 32 + scr;
                H[ps] = *(const uint4*)&hT[(size_t)cr * N_NODES + jbase + (ch + 1) * 64 + scj];
            }
        }
        // prefetch next mask group at end of each 4-chunk group (from LDS)
        u32 m8n[8];
#pragma unroll
        for (int w = 0; w < 8; ++w) m8n[w] = m8[w];
        if ((ch & 3) == 3 && more) {
            const u32* mp = &mk[(wid * 16 + n) * MSTR + ((ch >> 2) + 1) * 8];
#pragma unroll
            for (int w = 0; w < 8; ++w) m8n[w] = mp[w];
        }

        // build A-frags (w) for this chunk's 64 j
        short8 fa[2];
#pragma unroll
        for (int ks = 0; ks < 2; ++ks) {
            const int jl = ch * 64 + ks * 32 + quad * 8;
            float4 sa = *(const float4*)&s2s[jl];
            float4 sb = *(const float4*)&s2s[jl + 4];
            const float sv[8] = {sa.x, sa.y, sa.z, sa.w, sb.x, sb.y, sb.z, sb.w};
            union { u32 u[4]; short8 s; } cv;
#pragma unroll
            for (int jh = 0; jh < 4; ++jh) {
                float w2[2];
#pragma unroll
                for (int e = 0; e < 2; ++e) {
                    const int jj = jh * 2 + e;
                    const u32 word = m8[(jj & 3) * 2 + ((ch >> 1) & 1)];
                    const int sh = (ch & 1) * 16 + ks * 8 + quad * 2 + (jj >> 2);
                    const u32 mbit = (word >> sh) & 1u;
                    float sc = s1v + sv[jj];
                    sc = fmaxf(sc, LRELU_A * sc);
                    float w = mbit ? __expf(sc - MSH) : 0.f;
                    Lacc += w;
                    w2[e] = w;
                }
                cv.u[jh] = (u32)f2bf_rtn(w2[0]) | ((u32)f2bf_rtn(w2[1]) << 16);
            }
            fa[ks] = cv.s;
        }
        // 16 MFMAs from LDS (padded stride: uniform banks)
#pragma unroll
        for (int ct = 0; ct < 8; ++ct) {
            const int boff = (ct * 16 + n) * HSTR;
            short8 fb0 = *(const short8*)&hs[cur][boff + quad * 8];
            short8 fb1 = *(const short8*)&hs[cur][boff + 32 + quad * 8];
            acc[ct] = __builtin_amdgcn_mfma_f32_16x16x32_bf16(fa[0], fb0, acc[ct], 0, 0, 0);
            acc[ct] = __builtin_amdgcn_mfma_f32_16x16x32_bf16(fa[1], fb1, acc[ct], 0, 0, 0);
        }
        // write prefetched chunk to alternate buffer
        if (more) {
#pragma unroll
            for (int ps = 0; ps < 4; ++ps) {
                const int cr = ps * 32 + scr;
                *(uint4*)&hs[cur ^ 1][cr * HSTR + scj] = H[ps];
            }
        }
        __syncthreads();
#pragma unroll
        for (int w = 0; w < 8; ++w) m8[w] = m8n[w];
    }

    // L row-sum across quads
    Lacc += __shfl_xor(Lacc, 16, 64);
    Lacc += __shfl_xor(Lacc, 32, 64);
    if (lane < 16)
        Lpart[(size_t)blockIdx.y * N_NODES + i_lane] = Lacc;

    // O partials (C layout: row = quad*4+reg, col = ct*16+n)
    const size_t obase = (size_t)blockIdx.y * N_NODES * OUT_F;
#pragma unroll
    for (int ct = 0; ct < 8; ++ct) {
#pragma unroll
        for (int r = 0; r < 4; ++r) {
            const int i = i0 + wid * 16 + quad * 4 + r;
            Opart[obase + (size_t)i * OUT_F + ct * 16 + n] = acc[ct][r];
        }
    }
}

// ---------------- combine partials, normalize, column stats via atomics ----------------
// grid 512 x 256 thr; block = 16 i-rows
__global__ __launch_bounds__(256) void k_comb(const float* __restrict__ Opart, const float* __restrict__ Lpart,
                                              float* __restrict__ hp, float* __restrict__ cs, float* __restrict__ cq) {
    const int t = threadIdx.x;
    const int c = t & 127, half = t >> 7;
    const int ibase = blockIdx.x * 16;
    float sv = 0.f, sq = 0.f;
    for (int k = 0; k < 8; k++) {
        const int i = ibase + half + (k << 1);
        float o = 0.f, L = 0.f;
#pragma unroll
        for (int s = 0; s < NSPLIT; s++) {
            o += Opart[((size_t)s * N_NODES + i) * OUT_F + c];
            L += Lpart[(size_t)s * N_NODES + i];
        }
        float v = L > 0.f ? o / L : 0.f;
        hp[(size_t)i * OUT_F + c] = v;
        sv += v; sq += v * v;
    }
    __shared__ float red[256];
    red[t] = sv; __syncthreads();
    if (half == 0) atomicAdd(&cs[c], sv + red[t + 128]);
    __syncthreads(); red[t] = sq; __syncthreads();
    if (half == 0) atomicAdd(&cq[c], sq + red[t + 128]);
}

// ---------------- batchnorm + elu + f32 out ----------------
__global__ __launch_bounds__(256) void k_bn(const float* __restrict__ hp, const float* __restrict__ cs,
                                            const float* __restrict__ cq, const float* __restrict__ gamma,
                                            const float* __restrict__ beta, float* __restrict__ out) {
    const int idx = blockIdx.x * 256 + threadIdx.x;   // 1M
    const int c = idx & 127;
    const float mean = cs[c] * (1.f / N_NODES);
    const float var  = cq[c] * (1.f / N_NODES) - mean * mean;
    float x = (hp[idx] - mean) * rsqrtf(var + EPS_BN) * gamma[c] + beta[c];
    x = x > 0.f ? x : expm1f(x);
    out[idx] = x;
}

extern "C" void kernel_launch(void* const* d_in, const int* in_sizes, int n_in,
                              void* d_out, int out_size, void* d_ws, size_t ws_size,
                              hipStream_t stream) {
    (void)in_sizes; (void)n_in; (void)out_size; (void)ws_size;
    const float* inp   = (const float*)d_in[0];
    const int*   adj   = (const int*)d_in[1];
    const float* W     = (const float*)d_in[2];
    const float* a     = (const float*)d_in[3];
    const float* gamma = (const float*)d_in[4];
    const float* beta  = (const float*)d_in[5];
    float* out = (float*)d_out;

    char* wsb = (char*)d_ws;
    u16*   hamT = (u16*)wsb;   wsb += (size_t)OUT_F * IN_F * 2;               // 128 KB
    u16*   hT   = (u16*)wsb;   wsb += (size_t)OUT_F * N_NODES * 2;            // 2 MB
    float* s1   = (float*)wsb; wsb += N_NODES * 4;
    float* s2   = (float*)wsb; wsb += N_NODES * 4;
    float* Op   = (float*)wsb; wsb += (size_t)NSPLIT * N_NODES * OUT_F * 4;   // 32 MB
    float* Lp   = (float*)wsb; wsb += (size_t)NSPLIT * N_NODES * 4;
    float* hp   = (float*)wsb; wsb += (size_t)N_NODES * OUT_F * 4;            // 4 MB
    float* cs   = (float*)wsb; wsb += OUT_F * 4;
    float* cq   = (float*)wsb; wsb += OUT_F * 4;

    hipLaunchKernelGGL(k_hamT, dim3(256), dim3(256), 0, stream, W, hamT, s1, s2, cs, cq);
    hipLaunchKernelGGL(k_h,    dim3(128, 2), dim3(256), 0, stream, inp, hamT, a, hT, s1, s2);
    hipLaunchKernelGGL(k_att,  dim3(128, NSPLIT), dim3(256), 0, stream, adj, hT, s1, s2, Op, Lp);
    hipLaunchKernelGGL(k_comb, dim3(512), dim3(256), 0, stream, Op, Lp, hp, cs, cq);
    hipLaunchKernelGGL(k_bn,   dim3(4096), dim3(256), 0, stream, hp, cs, cq, gamma, beta, out);
}